// Round 2
// baseline (4329.954 us; speedup 1.0000x reference)
//
#include <hip/hip_runtime.h>

typedef __attribute__((ext_vector_type(8))) short short8;
typedef __attribute__((ext_vector_type(4))) float floatx4;

#define T_STEPS 1024
#define BATCH   256
#define INSZ    128
#define HID     512
#define OUTSZ   32

#define MFMA16(a,b,c) __builtin_amdgcn_mfma_f32_16x16x32_bf16((a),(b),(c),0,0,0)

// bf16 helpers (RNE)
static __device__ __forceinline__ short f2bf(float f) {
  unsigned int u = __float_as_uint(f);
  u += 0x7fffu + ((u >> 16) & 1u);
  return (short)(u >> 16);
}
static __device__ __forceinline__ float bf2f(short s) {
  return __uint_as_float(((unsigned int)(unsigned short)s) << 16);
}

static __device__ __forceinline__ void g2lds16(const void* g, void* l) {
  __builtin_amdgcn_global_load_lds(
      (const __attribute__((address_space(1))) unsigned int*)g,
      (__attribute__((address_space(3))) unsigned int*)l, 16, 0, 0);
}

// ---------------------------------------------------------------------------
// Pack weights into MFMA B-fragment-linear bf16 layouts.
// B-frag for 16x16x32: lane = ((k%32)/8)*16 + (n%16), elem j = k%8.
// frag id = kt*NT + nt ; pos = (frag*64 + lane)*8 + j
// ---------------------------------------------------------------------------
__global__ __launch_bounds__(256) void pack_kernel(
    const float* __restrict__ W_rec, const float* __restrict__ W_in,
    const float* __restrict__ W_out,
    short* __restrict__ w_rec_p, short* __restrict__ w_in_p,
    short* __restrict__ w_out_p) {
  int i = blockIdx.x * 256 + threadIdx.x;  // 0..262143
  {
    // W_rec[n][k] used as B[k][n]  (h @ W_rec^T)
    int n = i >> 9, k = i & 511;
    int pos = ((((k >> 5) * 32 + (n >> 4)) * 64 + ((k >> 3) & 3) * 16 + (n & 15)) << 3) + (k & 7);
    w_rec_p[pos] = f2bf(W_rec[i]);
  }
  if (i < INSZ * HID) {
    int k = i >> 9, n = i & 511;  // W_in[k][n] used as B[k][n]
    int pos = ((((k >> 5) * 32 + (n >> 4)) * 64 + ((k >> 3) & 3) * 16 + (n & 15)) << 3) + (k & 7);
    w_in_p[pos] = f2bf(W_in[i]);
  }
  if (i < HID * OUTSZ) {
    int k = i >> 5, o = i & 31;   // W_out[k][o] used as B[k][o], NT=2
    int pos = ((((k >> 5) * 2 + (o >> 4)) * 64 + ((k >> 3) & 3) * 16 + (o & 15)) << 3) + (k & 7);
    w_out_p[pos] = f2bf(W_out[i]);
  }
}

// ---------------------------------------------------------------------------
// x_proj GEMM for one chunk: [C*256, 128] @ [128, 512] + b_rec -> bf16 xp
// grid = C blocks x 256 thr; block handles 16 M-tiles (= 1 timestep).
// ---------------------------------------------------------------------------
__global__ __launch_bounds__(256) void xproj_kernel(
    const float* __restrict__ inputs, const short* __restrict__ w_in_p,
    const float* __restrict__ b_rec, short* __restrict__ xp) {
  const int wave = threadIdx.x >> 6, lane = threadIdx.x & 63;
  const int l15 = lane & 15, q = lane >> 4;

  short8 bfr[8][4];
  #pragma unroll
  for (int i = 0; i < 8; ++i)
    #pragma unroll
    for (int kt = 0; kt < 4; ++kt)
      bfr[i][kt] = *(const short8*)(w_in_p + (((kt * 32 + wave * 8 + i) * 64 + lane) << 3));

  float brv[8];
  #pragma unroll
  for (int i = 0; i < 8; ++i) brv[i] = b_rec[(wave * 8 + i) * 16 + l15];

  for (int it = 0; it < 16; ++it) {
    int mt = blockIdx.x * 16 + it;
    const float* arow = inputs + (size_t)(mt * 16 + l15) * INSZ + q * 8;
    short8 afr[4];
    #pragma unroll
    for (int kt = 0; kt < 4; ++kt) {
      short8 s;
      #pragma unroll
      for (int j = 0; j < 8; ++j) s[j] = f2bf(arow[kt * 32 + j]);
      afr[kt] = s;
    }
    floatx4 acc[8];
    #pragma unroll
    for (int i = 0; i < 8; ++i) acc[i] = (floatx4){0.f, 0.f, 0.f, 0.f};
    #pragma unroll
    for (int kt = 0; kt < 4; ++kt)
      #pragma unroll
      for (int i = 0; i < 8; ++i)
        acc[i] = MFMA16(afr[kt], bfr[i][kt], acc[i]);
    #pragma unroll
    for (int i = 0; i < 8; ++i) {
      int col = (wave * 8 + i) * 16 + l15;
      #pragma unroll
      for (int r = 0; r < 4; ++r) {
        int row = mt * 16 + q * 4 + r;
        xp[(size_t)row * HID + col] = f2bf(acc[i][r] + brv[i]);
      }
    }
  }
}

// ---------------------------------------------------------------------------
// Sequential scan over Tc steps. 16 blocks x 512 thr (8 waves). Block owns 16
// batch rows. W_rec resident: ktiles 0..11 in VGPRs (192/lane), 12..15 in LDS.
// fp32 state in registers + carried in global h_carry across chunk launches.
// LDS: 131072 + 16384 + 16384 = 163840 B.
// ---------------------------------------------------------------------------
__global__ __launch_bounds__(512, 2) void scan_kernel(
    const short* __restrict__ w_rec_p, const short* __restrict__ xp,
    short* __restrict__ hs, float* __restrict__ h_carry,
    int Tc, int first) {
  __shared__ __align__(16) short w_lds[4 * 32 * 512];
  __shared__ __align__(16) short h_bf[16 * 512];
  __shared__ __align__(16) short xp_s[16 * 512];

  const int tid = threadIdx.x;
  const int wave = tid >> 6, lane = tid & 63;
  const int l15 = lane & 15, q = lane >> 4;
  const int slab = blockIdx.x * 16;

  // resident weight fragments, ktiles 0..11 (wave owns cols [wave*64, +64))
  short8 wreg[12][4];
  #pragma unroll
  for (int kt = 0; kt < 12; ++kt)
    #pragma unroll
    for (int nt = 0; nt < 4; ++nt)
      wreg[kt][nt] = *(const short8*)(w_rec_p + (((kt * 32 + wave * 4 + nt) * 64 + lane) << 3));

  // ktiles 12..15 -> LDS (frag-linear region contiguous in w_rec_p)
  for (int e = tid * 8; e < 4 * 32 * 512; e += 512 * 8)
    *(short8*)(w_lds + e) = *(const short8*)(w_rec_p + 12 * 32 * 512 + e);

  // load carried state (or zeros on first chunk) into registers + swizzled LDS
  float hold[4][4];
  #pragma unroll
  for (int nt = 0; nt < 4; ++nt) {
    int col = wave * 64 + nt * 16 + l15;
    int ck = col >> 3, cl = col & 7;
    #pragma unroll
    for (int r = 0; r < 4; ++r) {
      int row = q * 4 + r;
      float v = first ? 0.f : h_carry[(size_t)(slab + row) * HID + col];
      hold[nt][r] = v;
      h_bf[row * 512 + ((ck ^ row) << 3) + cl] = f2bf(v);
    }
  }

  const float alpha = (float)(0.1 / 100.0);
  const float onem  = (float)(1.0 - 0.1 / 100.0);

  __syncthreads();

  for (int t = 0; t < Tc; ++t) {
    // prefetch xp[t] slab (16 rows x 512) into LDS; consumed after barrier
    {
      const short* xg = xp + ((size_t)t * BATCH + slab) * HID;
      #pragma unroll
      for (int c = 0; c < 2; ++c) {
        int off = (wave * 2 + c) * 512;
        g2lds16(xg + off + lane * 8, xp_s + off);  // HW adds lane*16B to LDS base
      }
    }

    floatx4 acc[4];
    #pragma unroll
    for (int nt = 0; nt < 4; ++nt) acc[nt] = (floatx4){0.f, 0.f, 0.f, 0.f};

    #pragma unroll
    for (int kt = 0; kt < 16; ++kt) {
      // A-frag: h[m=l15][k=kt*32+q*8+j], chunk (kt*4+q) XOR-swizzled by row
      short8 afr = *(const short8*)(h_bf + l15 * 512 + (((kt * 4 + q) ^ l15) << 3));
      if (kt < 12) {
        #pragma unroll
        for (int nt = 0; nt < 4; ++nt)
          acc[nt] = MFMA16(afr, wreg[kt][nt], acc[nt]);
      } else {
        #pragma unroll
        for (int nt = 0; nt < 4; ++nt) {
          short8 bfr = *(const short8*)(w_lds + (((kt - 12) * 32 + wave * 4 + nt) << 9) + lane * 8);
          acc[nt] = MFMA16(afr, bfr, acc[nt]);
        }
      }
    }
    __syncthreads();  // drains vmcnt: xp_s ready; all h_bf reads complete

    // epilogue: CTRNN update in fp32 registers, write bf16 h to LDS
    #pragma unroll
    for (int nt = 0; nt < 4; ++nt) {
      int col = wave * 64 + nt * 16 + l15;
      int ck = col >> 3, cl = col & 7;
      #pragma unroll
      for (int r = 0; r < 4; ++r) {
        int row = q * 4 + r;
        float pre = acc[nt][r] + bf2f(xp_s[row * 512 + col]);
        float hn = onem * hold[nt][r] + alpha * fmaxf(pre, 0.f);
        hold[nt][r] = hn;
        h_bf[row * 512 + ((ck ^ row) << 3) + cl] = f2bf(hn);
      }
    }
    __syncthreads();  // h_bf complete

    // coalesced copy h_bf -> hs[t] (unswizzle on read)
    {
      int e = tid * 16;
      int row = e >> 9, c0 = (e & 511) >> 3;
      short8 v0 = *(const short8*)(h_bf + row * 512 + ((c0 ^ row) << 3));
      short8 v1 = *(const short8*)(h_bf + row * 512 + (((c0 + 1) ^ row) << 3));
      short* dst = hs + ((size_t)t * BATCH + slab) * HID + e;
      *(short8*)(dst) = v0;
      *(short8*)(dst + 8) = v1;
    }
  }

  // write carried state for next chunk
  #pragma unroll
  for (int nt = 0; nt < 4; ++nt) {
    int col = wave * 64 + nt * 16 + l15;
    #pragma unroll
    for (int r = 0; r < 4; ++r)
      h_carry[(size_t)(slab + q * 4 + r) * HID + col] = hold[nt][r];
  }
}

// ---------------------------------------------------------------------------
// Output GEMM for one chunk: [C*256, 512] @ [512, 32] + b_out -> fp32 out
// grid = C blocks x 256 thr; wave handles 4 M-tiles via padded LDS staging.
// ---------------------------------------------------------------------------
__global__ __launch_bounds__(256) void out_kernel(
    const short* __restrict__ hs, const short* __restrict__ w_out_p,
    const float* __restrict__ b_out, float* __restrict__ out) {
  __shared__ __align__(16) short a_lds[4][16 * 520];
  const int wave = threadIdx.x >> 6, lane = threadIdx.x & 63;
  const int l15 = lane & 15, q = lane >> 4;

  short8 bfr[16][2];
  #pragma unroll
  for (int kt = 0; kt < 16; ++kt)
    #pragma unroll
    for (int ot = 0; ot < 2; ++ot)
      bfr[kt][ot] = *(const short8*)(w_out_p + (((kt * 2 + ot) * 64 + lane) << 3));
  float bov[2] = { b_out[l15], b_out[16 + l15] };

  for (int it = 0; it < 4; ++it) {
    int mt = blockIdx.x * 16 + wave * 4 + it;
    const short* src = hs + (size_t)mt * (16 * 512);
    short* al = &a_lds[wave][0];
    #pragma unroll
    for (int r = 0; r < 16; ++r)
      *(short8*)(al + r * 520 + lane * 8) = *(const short8*)(src + r * 512 + lane * 8);
    // wave-private LDS tile: in-wave DS ordering suffices, no barrier

    floatx4 acc[2];
    acc[0] = (floatx4){0.f, 0.f, 0.f, 0.f};
    acc[1] = (floatx4){0.f, 0.f, 0.f, 0.f};
    #pragma unroll
    for (int kt = 0; kt < 16; ++kt) {
      short8 afr = *(const short8*)(al + l15 * 520 + kt * 32 + q * 8);
      acc[0] = MFMA16(afr, bfr[kt][0], acc[0]);
      acc[1] = MFMA16(afr, bfr[kt][1], acc[1]);
    }
    #pragma unroll
    for (int ot = 0; ot < 2; ++ot)
      #pragma unroll
      for (int r = 0; r < 4; ++r)
        out[(size_t)(mt * 16 + q * 4 + r) * OUTSZ + ot * 16 + l15] = acc[ot][r] + bov[ot];
  }
}

// ---------------------------------------------------------------------------
extern "C" void kernel_launch(void* const* d_in, const int* in_sizes, int n_in,
                              void* d_out, int out_size, void* d_ws, size_t ws_size,
                              hipStream_t stream) {
  const float* inputs = (const float*)d_in[0];  // [1024,256,128]
  const float* W_rec  = (const float*)d_in[1];  // [512,512]
  const float* W_in   = (const float*)d_in[2];  // [128,512]
  const float* b_rec  = (const float*)d_in[3];  // [512]
  const float* W_out  = (const float*)d_in[4];  // [512,32]
  const float* b_out  = (const float*)d_in[5];  // [32]
  float* out = (float*)d_out;                   // [1024,256,32]

  char* ws = (char*)d_ws;
  // fixed region (< 2 MB): packed weights + fp32 h carry
  short* w_rec_p = (short*)(ws);                       // 512 KB
  short* w_in_p  = (short*)(ws + 524288);              // 128 KB
  short* w_out_p = (short*)(ws + 655360);              //  32 KB
  float* h_carry = (float*)(ws + 688128);              // 512 KB
  const size_t fixed_end = 2u << 20;                   // 2 MB

  // chunked buffers: xp + hs, each C*256*512 bf16 = C*256 KB
  const size_t per_step = (size_t)BATCH * HID * 2 * 2; // 512 KB / step
  int chunk = T_STEPS;
  while (chunk > 1 && fixed_end + (size_t)chunk * per_step > ws_size) chunk >>= 1;
  if (fixed_end + (size_t)chunk * per_step > ws_size) return;  // ws too small
  const int nchunks = T_STEPS / chunk;

  short* xp = (short*)(ws + fixed_end);
  short* hs = (short*)(ws + fixed_end + (size_t)chunk * BATCH * HID * 2);

  pack_kernel<<<1024, 256, 0, stream>>>(W_rec, W_in, W_out, w_rec_p, w_in_p, w_out_p);

  for (int c = 0; c < nchunks; ++c) {
    const float* in_c  = inputs + (size_t)c * chunk * BATCH * INSZ;
    float*       out_c = out    + (size_t)c * chunk * BATCH * OUTSZ;
    xproj_kernel<<<chunk, 256, 0, stream>>>(in_c, w_in_p, b_rec, xp);
    scan_kernel <<<   16, 512, 0, stream>>>(w_rec_p, xp, hs, h_carry, chunk, c == 0);
    out_kernel  <<<chunk, 256, 0, stream>>>(hs, w_out_p, b_out, out_c);
  }
}